// Round 12
// baseline (1233.421 us; speedup 1.0000x reference)
//
#include <hip/hip_runtime.h>
#include <hip/hip_bf16.h>

// out = (sum_k h[k] * S_k) @ x  — COO SpMM, bucket-binned, atomic-free accumulate.
//
// Round-11 lesson: scatter slowness is NOT payload format (int2 vs split —
// identical 221MB/268us profiles). Model: frontier lines (streams x 16
// WGs/XCD x 64B) must fit per-XCD L2 *alongside* the spmv's hot bf16-x copy
// (12.8MB, replicated per XCD, replacement-favored). r5's 3.2MB/XCD barely
// fit without xh; with xh it thrashes. Fix: streams = 1563 (bucket only,
// no parity) -> 1.6MB/XCD frontier. Parity moves into spmv: payload p.x is
// wave-uniform, so wave wv skips rl&1 != wv via uniform scalar branch (no
// divergence, gathers only on match). Shared 16KB acc stays race-free.
//
// ws: cnt[1563*GWG] | ssBeg[1564] | pad | payload[KE] int2 | xh[N*64] bf16

#define RPB   64           // rows per bucket
#define GWG   128          // count/scatter workgroups

static __global__ __launch_bounds__(1024) void count_kernel(
    const int* __restrict__ rows, int* __restrict__ cnt,
    int KE, int NSTREAM, int chunk)
{
    extern __shared__ int hist[];              // NSTREAM ints
    const int g = blockIdx.x;
    for (int j = threadIdx.x; j < NSTREAM; j += blockDim.x) hist[j] = 0;
    __syncthreads();
    const int lo = g * chunk;
    const int hi = min(lo + chunk, KE);
    for (int e = lo + threadIdx.x; e < hi; e += blockDim.x)
        atomicAdd(&hist[rows[e] >> 6], 1);
    __syncthreads();
    for (int j = threadIdx.x; j < NSTREAM; j += blockDim.x)
        cnt[(size_t)j * GWG + g] = hist[j];
}

// B1: per-stream exclusive scan of its GWG counts (in place); total -> ssBeg[s]
static __global__ __launch_bounds__(GWG) void scan1_kernel(
    int* __restrict__ cnt, int* __restrict__ ssBeg)
{
    __shared__ int tmp[GWG];
    const int s = blockIdx.x;
    const int t = threadIdx.x;
    const int v = cnt[(size_t)s * GWG + t];
    tmp[t] = v;
    __syncthreads();
    for (int d = 1; d < GWG; d <<= 1) {
        int u = (t >= d) ? tmp[t - d] : 0;
        __syncthreads();
        tmp[t] += u;
        __syncthreads();
    }
    cnt[(size_t)s * GWG + t] = tmp[t] - v;     // exclusive
    if (t == GWG - 1) ssBeg[s] = tmp[t];       // stream total
}

// B2: exclusive scan of ssBeg[0..n) in place; ssBeg[n] = grand total
static __global__ __launch_bounds__(1024) void scan2_kernel(
    int* __restrict__ a, int n)
{
    __shared__ int sums[1024];
    const int t = threadIdx.x;
    const int chunk = (n + 1023) >> 10;
    const int lo = t * chunk;
    const int hi = min(lo + chunk, n);
    int s = 0;
    for (int i = lo; i < hi; ++i) s += a[i];
    sums[t] = s;
    __syncthreads();
    for (int d = 1; d < 1024; d <<= 1) {
        int v = (t >= d) ? sums[t - d] : 0;
        __syncthreads();
        sums[t] += v;
        __syncthreads();
    }
    int run = (t > 0) ? sums[t - 1] : 0;
    for (int i = lo; i < hi; ++i) {
        const int cv = a[i];
        a[i] = run;
        run += cv;
    }
    if (t == 1023) a[n] = sums[1023];
}

// B3: cnt[s][g] += stream base
static __global__ __launch_bounds__(1024) void scan3_kernel(
    int* __restrict__ cnt, const int* __restrict__ ssBeg, int total)
{
    const int i = blockIdx.x * blockDim.x + threadIdx.x;
    if (i < total) cnt[i] += ssBeg[i >> 7];    // i / GWG (GWG=128)
}

static __global__ __launch_bounds__(1024) void scatter_kernel(
    const int*   __restrict__ rows,
    const int*   __restrict__ cols,
    const float* __restrict__ vals,
    const float* __restrict__ h,
    const int*   __restrict__ cnt,
    int2*        __restrict__ payload,
    int KE, int E, int K, int NSTREAM, int chunk)
{
    extern __shared__ int lcur[];              // NSTREAM cursors
    const int g = blockIdx.x;
    for (int j = threadIdx.x; j < NSTREAM; j += blockDim.x)
        lcur[j] = cnt[(size_t)j * GWG + g];
    __syncthreads();
    const int lo = g * chunk;
    const int hi = min(lo + chunk, KE);
    if (lo >= hi) return;
    const int k0 = lo / E;
    const int k1 = min((hi - 1) / E, K - 1);
    for (int k = k0; k <= k1; ++k) {
        const float hk = h[k];
        const int s0 = max(lo, k * E);
        const int s1 = min(hi, (k + 1) * E);
        for (int e = s0 + threadIdx.x; e < s1; e += blockDim.x) {
            const int r = rows[e];
            const int pos = atomicAdd(&lcur[r >> 6], 1);  // int LDS atomic
            payload[pos] = make_int2(((r & 63) << 17) | cols[e],
                                     __float_as_int(hk * vals[e]));
        }
    }
}

// x (f32) -> xh (bf16), vectorized: float4 in, ushort4 out
static __global__ __launch_bounds__(256) void convert_kernel(
    const float* __restrict__ x, ushort* __restrict__ xh, int n4)
{
    const int i = blockIdx.x * blockDim.x + threadIdx.x;
    if (i >= n4) return;
    const float4 v = ((const float4*)x)[i];
    ushort4 o;
    o.x = __bfloat16_as_ushort(__float2bfloat16(v.x));
    o.y = __bfloat16_as_ushort(__float2bfloat16(v.y));
    o.z = __bfloat16_as_ushort(__float2bfloat16(v.z));
    o.w = __bfloat16_as_ushort(__float2bfloat16(v.w));
    ((ushort4*)xh)[i] = o;
}

// Tier A: bf16 gather; wave wv processes only edges with rl&1 == wv
// (p.x is wave-uniform -> uniform branch, no divergence, no wasted gathers).
static __global__ __launch_bounds__(128) void spmv_bf16_kernel(
    const int*    __restrict__ ssBeg,
    const int2*   __restrict__ payload,
    const ushort* __restrict__ xh,
    float*        __restrict__ out,
    int N)
{
    __shared__ float acc[RPB * 64];            // 16KB, shared; parity-disjoint rows
    const int b = blockIdx.x;
    for (int i = threadIdx.x; i < RPB * 64; i += 128) acc[i] = 0.f;
    __syncthreads();

    const int lane = threadIdx.x & 63;
    const int wv   = threadIdx.x >> 6;         // parity this wave owns
    int e        = ssBeg[b];
    const int be = ssBeg[b + 1];

    while (e + 32 <= be) {
        int2 pp[32];
        float xv[32];
        #pragma unroll
        for (int j = 0; j < 32; ++j) pp[j] = payload[e + j];
        #pragma unroll
        for (int j = 0; j < 32; ++j) {
            if ((((unsigned)pp[j].x >> 17) & 1u) == (unsigned)wv)
                xv[j] = __bfloat162float(__ushort_as_bfloat16(
                            xh[(size_t)(pp[j].x & 0x1FFFF) * 64 + lane]));
        }
        #pragma unroll
        for (int j = 0; j < 32; ++j) {
            if ((((unsigned)pp[j].x >> 17) & 1u) == (unsigned)wv)
                acc[(pp[j].x >> 17) * 64 + lane] +=
                    __int_as_float(pp[j].y) * xv[j];
        }
        e += 32;
    }
    for (; e < be; ++e) {
        const int2 p = payload[e];
        if ((((unsigned)p.x >> 17) & 1u) == (unsigned)wv) {
            const float xv2 = __bfloat162float(__ushort_as_bfloat16(
                                  xh[(size_t)(p.x & 0x1FFFF) * 64 + lane]));
            acc[(p.x >> 17) * 64 + lane] += __int_as_float(p.y) * xv2;
        }
    }
    __syncthreads();

    const int base = b * RPB;
    const int nrow = min(RPB, N - base);
    for (int i = threadIdx.x; i < nrow * 64; i += 128)
        out[(size_t)base * 64 + i] = acc[i];
}

// Tier B: f32 gather variant (ws too small for xh), same parity-skip scheme.
static __global__ __launch_bounds__(128) void spmv_f32_kernel(
    const int*  __restrict__ ssBeg,
    const int2* __restrict__ payload,
    const float* __restrict__ x,
    float*       __restrict__ out,
    int N)
{
    __shared__ float acc[RPB * 64];
    const int b = blockIdx.x;
    for (int i = threadIdx.x; i < RPB * 64; i += 128) acc[i] = 0.f;
    __syncthreads();

    const int lane = threadIdx.x & 63;
    const int wv   = threadIdx.x >> 6;
    int e        = ssBeg[b];
    const int be = ssBeg[b + 1];

    while (e + 32 <= be) {
        int2 pp[32];
        float xv[32];
        #pragma unroll
        for (int j = 0; j < 32; ++j) pp[j] = payload[e + j];
        #pragma unroll
        for (int j = 0; j < 32; ++j) {
            if ((((unsigned)pp[j].x >> 17) & 1u) == (unsigned)wv)
                xv[j] = x[(size_t)(pp[j].x & 0x1FFFF) * 64 + lane];
        }
        #pragma unroll
        for (int j = 0; j < 32; ++j) {
            if ((((unsigned)pp[j].x >> 17) & 1u) == (unsigned)wv)
                acc[(pp[j].x >> 17) * 64 + lane] +=
                    __int_as_float(pp[j].y) * xv[j];
        }
        e += 32;
    }
    for (; e < be; ++e) {
        const int2 p = payload[e];
        if ((((unsigned)p.x >> 17) & 1u) == (unsigned)wv)
            acc[(p.x >> 17) * 64 + lane] +=
                __int_as_float(p.y) * x[(size_t)(p.x & 0x1FFFF) * 64 + lane];
    }
    __syncthreads();

    const int base = b * RPB;
    const int nrow = min(RPB, N - base);
    for (int i = threadIdx.x; i < nrow * 64; i += 128)
        out[(size_t)base * 64 + i] = acc[i];
}

// Round-1 fallback (atomic scatter) if ws is too small for binning at all.
static __global__ __launch_bounds__(256) void gtconv_scatter(
    const float* __restrict__ x, const float* __restrict__ h,
    const float* __restrict__ vals, const int* __restrict__ rows,
    const int* __restrict__ cols, float* __restrict__ out, int KE, int E)
{
    const int lane = threadIdx.x & 63;
    int wave = (blockIdx.x * blockDim.x + threadIdx.x) >> 6;
    const int nwaves = (gridDim.x * blockDim.x) >> 6;
    for (int e = wave; e < KE; e += nwaves) {
        float w = h[e / E] * vals[e];
        float xv = x[(size_t)cols[e] * 64 + lane];
        unsafeAtomicAdd(&out[(size_t)rows[e] * 64 + lane], xv * w);
    }
}

extern "C" void kernel_launch(void* const* d_in, const int* in_sizes, int n_in,
                              void* d_out, int out_size, void* d_ws, size_t ws_size,
                              hipStream_t stream) {
    const float* x    = (const float*)d_in[0];
    const float* h    = (const float*)d_in[1];
    const float* vals = (const float*)d_in[2];
    const int*   rows = (const int*)d_in[3];
    const int*   cols = (const int*)d_in[4];
    float* out = (float*)d_out;

    const int K  = in_sizes[1];
    const int KE = in_sizes[2];
    const int E  = KE / K;
    const int F  = 64;
    const int N  = in_sizes[0] / F;
    const int NB      = (N + RPB - 1) / RPB;       // 1563
    const int NSTREAM = NB;                        // 1563 (bucket only)

    const size_t lds_need = (size_t)NSTREAM * 4;   // count/scatter LDS (6.3KB)
    const size_t cnt_off  = 0;
    const size_t cnt_sz   = (size_t)NSTREAM * GWG * 4;
    const size_t ss_off   = cnt_off + cnt_sz;
    const size_t ss_sz    = (size_t)(NSTREAM + 1) * 4;
    const size_t pl_off   = (ss_off + ss_sz + 15) & ~(size_t)15;
    const size_t base_need = pl_off + (size_t)KE * 8;
    const size_t xh_off   = (base_need + 63) & ~(size_t)63;
    const size_t full_need = xh_off + (size_t)N * F * 2;

    if (ws_size < base_need || lds_need > 64 * 1024) {
        hipMemsetAsync(out, 0, (size_t)out_size * sizeof(float), stream);
        gtconv_scatter<<<8192, 256, 0, stream>>>(x, h, vals, rows, cols, out, KE, E);
        return;
    }

    char* ws = (char*)d_ws;
    int*    cnt     = (int*)(ws + cnt_off);
    int*    ssBeg   = (int*)(ws + ss_off);
    int2*   payload = (int2*)(ws + pl_off);
    ushort* xh      = (ushort*)(ws + xh_off);
    const bool use_bf16 = (ws_size >= full_need);

    if (use_bf16) {
        const int n4 = (N * F) / 4;
        convert_kernel<<<(n4 + 255) / 256, 256, 0, stream>>>(x, xh, n4);
    }

    const int chunk = (KE + GWG - 1) / GWG;
    count_kernel<<<GWG, 1024, lds_need, stream>>>(rows, cnt, KE, NSTREAM, chunk);
    scan1_kernel<<<NSTREAM, GWG, 0, stream>>>(cnt, ssBeg);
    scan2_kernel<<<1, 1024, 0, stream>>>(ssBeg, NSTREAM);
    const int total = NSTREAM * GWG;
    scan3_kernel<<<(total + 1023) / 1024, 1024, 0, stream>>>(cnt, ssBeg, total);
    scatter_kernel<<<GWG, 1024, lds_need, stream>>>(rows, cols, vals, h, cnt,
                                                    payload, KE, E, K, NSTREAM, chunk);
    if (use_bf16)
        spmv_bf16_kernel<<<NB, 128, 0, stream>>>(ssBeg, payload, xh, out, N);
    else
        spmv_f32_kernel<<<NB, 128, 0, stream>>>(ssBeg, payload, x, out, N);
}

// Round 13
// 508.943 us; speedup vs baseline: 2.4235x; 2.4235x over previous
//
#include <hip/hip_runtime.h>
#include <hip/hip_bf16.h>

// out = (sum_k h[k] * S_k) @ x  — COO SpMM, bucket-binned, atomic-free accumulate.
//
// Proven pieces combined:
//  * Binning with NSTREAM=1563 buckets (RPB=64, no parity), GWG=128:
//    frontier lines = 1563 x 16 WGs/XCD x 64B = 1.6MB/XCD -> fits per-XCD L2
//    even with the hot 12.8MB bf16-x copy resident (r12: scatter ~55us).
//    (3126 streams + xh resident = thrash, 268us, r11.)
//  * spmv with UNCONDITIONAL 16-deep gather pipeline (r5/r11 body) + bf16
//    gather (r8/r11: halves fetched bytes). r12's parity-branch broke load
//    clustering (1134us) -> instead split each bucket POSITIONALLY across
//    2 waves, each with a PRIVATE 16KB acc copy (32KB LDS, race-free by
//    construction, zero branches), merged at the end.
//
// ws: cnt[1563*GWG] | ssBeg[1564] | pad | payload[KE] int2 | xh[N*64] bf16

#define RPB   64           // rows per bucket
#define GWG   128          // count/scatter workgroups

static __global__ __launch_bounds__(1024) void count_kernel(
    const int* __restrict__ rows, int* __restrict__ cnt,
    int KE, int NSTREAM, int chunk)
{
    extern __shared__ int hist[];              // NSTREAM ints
    const int g = blockIdx.x;
    for (int j = threadIdx.x; j < NSTREAM; j += blockDim.x) hist[j] = 0;
    __syncthreads();
    const int lo = g * chunk;
    const int hi = min(lo + chunk, KE);
    for (int e = lo + threadIdx.x; e < hi; e += blockDim.x)
        atomicAdd(&hist[rows[e] >> 6], 1);
    __syncthreads();
    for (int j = threadIdx.x; j < NSTREAM; j += blockDim.x)
        cnt[(size_t)j * GWG + g] = hist[j];
}

// B1: per-stream exclusive scan of its GWG counts (in place); total -> ssBeg[s]
static __global__ __launch_bounds__(GWG) void scan1_kernel(
    int* __restrict__ cnt, int* __restrict__ ssBeg)
{
    __shared__ int tmp[GWG];
    const int s = blockIdx.x;
    const int t = threadIdx.x;
    const int v = cnt[(size_t)s * GWG + t];
    tmp[t] = v;
    __syncthreads();
    for (int d = 1; d < GWG; d <<= 1) {
        int u = (t >= d) ? tmp[t - d] : 0;
        __syncthreads();
        tmp[t] += u;
        __syncthreads();
    }
    cnt[(size_t)s * GWG + t] = tmp[t] - v;     // exclusive
    if (t == GWG - 1) ssBeg[s] = tmp[t];       // stream total
}

// B2: exclusive scan of ssBeg[0..n) in place; ssBeg[n] = grand total
static __global__ __launch_bounds__(1024) void scan2_kernel(
    int* __restrict__ a, int n)
{
    __shared__ int sums[1024];
    const int t = threadIdx.x;
    const int chunk = (n + 1023) >> 10;
    const int lo = t * chunk;
    const int hi = min(lo + chunk, n);
    int s = 0;
    for (int i = lo; i < hi; ++i) s += a[i];
    sums[t] = s;
    __syncthreads();
    for (int d = 1; d < 1024; d <<= 1) {
        int v = (t >= d) ? sums[t - d] : 0;
        __syncthreads();
        sums[t] += v;
        __syncthreads();
    }
    int run = (t > 0) ? sums[t - 1] : 0;
    for (int i = lo; i < hi; ++i) {
        const int cv = a[i];
        a[i] = run;
        run += cv;
    }
    if (t == 1023) a[n] = sums[1023];
}

// B3: cnt[s][g] += stream base
static __global__ __launch_bounds__(1024) void scan3_kernel(
    int* __restrict__ cnt, const int* __restrict__ ssBeg, int total)
{
    const int i = blockIdx.x * blockDim.x + threadIdx.x;
    if (i < total) cnt[i] += ssBeg[i >> 7];    // i / GWG (GWG=128)
}

static __global__ __launch_bounds__(1024) void scatter_kernel(
    const int*   __restrict__ rows,
    const int*   __restrict__ cols,
    const float* __restrict__ vals,
    const float* __restrict__ h,
    const int*   __restrict__ cnt,
    int2*        __restrict__ payload,
    int KE, int E, int K, int NSTREAM, int chunk)
{
    extern __shared__ int lcur[];              // NSTREAM cursors
    const int g = blockIdx.x;
    for (int j = threadIdx.x; j < NSTREAM; j += blockDim.x)
        lcur[j] = cnt[(size_t)j * GWG + g];
    __syncthreads();
    const int lo = g * chunk;
    const int hi = min(lo + chunk, KE);
    if (lo >= hi) return;
    const int k0 = lo / E;
    const int k1 = min((hi - 1) / E, K - 1);
    for (int k = k0; k <= k1; ++k) {
        const float hk = h[k];
        const int s0 = max(lo, k * E);
        const int s1 = min(hi, (k + 1) * E);
        for (int e = s0 + threadIdx.x; e < s1; e += blockDim.x) {
            const int r = rows[e];
            const int pos = atomicAdd(&lcur[r >> 6], 1);  // int LDS atomic
            payload[pos] = make_int2(((r & 63) << 17) | cols[e],
                                     __float_as_int(hk * vals[e]));
        }
    }
}

// x (f32) -> xh (bf16), vectorized: float4 in, ushort4 out
static __global__ __launch_bounds__(256) void convert_kernel(
    const float* __restrict__ x, ushort* __restrict__ xh, int n4)
{
    const int i = blockIdx.x * blockDim.x + threadIdx.x;
    if (i >= n4) return;
    const float4 v = ((const float4*)x)[i];
    ushort4 o;
    o.x = __bfloat16_as_ushort(__float2bfloat16(v.x));
    o.y = __bfloat16_as_ushort(__float2bfloat16(v.y));
    o.z = __bfloat16_as_ushort(__float2bfloat16(v.z));
    o.w = __bfloat16_as_ushort(__float2bfloat16(v.w));
    ((ushort4*)xh)[i] = o;
}

// Tier A: bf16 gather. 2 waves per block; wave wv takes the POSITIONAL half
// of the bucket's payload, accumulating into a PRIVATE 16KB LDS copy.
// Unconditional 16-deep pipeline (the proven r5/r11 loop body).
static __global__ __launch_bounds__(128) void spmv_bf16_kernel(
    const int*    __restrict__ ssBeg,
    const int2*   __restrict__ payload,
    const ushort* __restrict__ xh,
    float*        __restrict__ out,
    int N)
{
    __shared__ float acc[2][RPB * 64];         // wave-private copies, 32KB
    const int tid = threadIdx.x;
    float* accf = (float*)acc;
    for (int i = tid; i < 2 * RPB * 64; i += 128) accf[i] = 0.f;
    __syncthreads();

    const int b    = blockIdx.x;
    const int lane = tid & 63;
    const int wv   = tid >> 6;                 // 0..1 positional half
    float* ac = acc[wv];

    const int ss = ssBeg[b];
    const int se = ssBeg[b + 1];
    const int half = (se - ss) >> 1;
    int e        = ss + half * wv;
    const int be = wv ? se : (ss + half);

    while (e + 16 <= be) {
        int2 pa[8], pb[8];
        float xa[8], xb[8];
        #pragma unroll
        for (int j = 0; j < 8; ++j) pa[j] = payload[e + j];
        #pragma unroll
        for (int j = 0; j < 8; ++j) pb[j] = payload[e + 8 + j];
        #pragma unroll
        for (int j = 0; j < 8; ++j)
            xa[j] = __bfloat162float(__ushort_as_bfloat16(
                        xh[(size_t)(pa[j].x & 0x1FFFF) * 64 + lane]));
        #pragma unroll
        for (int j = 0; j < 8; ++j)
            xb[j] = __bfloat162float(__ushort_as_bfloat16(
                        xh[(size_t)(pb[j].x & 0x1FFFF) * 64 + lane]));
        #pragma unroll
        for (int j = 0; j < 8; ++j)
            ac[(pa[j].x >> 17) * 64 + lane] += __int_as_float(pa[j].y) * xa[j];
        #pragma unroll
        for (int j = 0; j < 8; ++j)
            ac[(pb[j].x >> 17) * 64 + lane] += __int_as_float(pb[j].y) * xb[j];
        e += 16;
    }
    for (; e < be; ++e) {
        const int2 p = payload[e];
        const float xv = __bfloat162float(__ushort_as_bfloat16(
                             xh[(size_t)(p.x & 0x1FFFF) * 64 + lane]));
        ac[(p.x >> 17) * 64 + lane] += __int_as_float(p.y) * xv;
    }
    __syncthreads();

    // merge the two copies and store
    const int base = b * RPB;
    const int nrow = min(RPB, N - base);
    for (int i = tid; i < nrow * 64; i += 128)
        out[(size_t)base * 64 + i] = acc[0][i] + acc[1][i];
}

// Tier B: f32 gather, same structure (ws too small for xh).
static __global__ __launch_bounds__(128) void spmv_f32_kernel(
    const int*  __restrict__ ssBeg,
    const int2* __restrict__ payload,
    const float* __restrict__ x,
    float*       __restrict__ out,
    int N)
{
    __shared__ float acc[2][RPB * 64];
    const int tid = threadIdx.x;
    float* accf = (float*)acc;
    for (int i = tid; i < 2 * RPB * 64; i += 128) accf[i] = 0.f;
    __syncthreads();

    const int b    = blockIdx.x;
    const int lane = tid & 63;
    const int wv   = tid >> 6;
    float* ac = acc[wv];

    const int ss = ssBeg[b];
    const int se = ssBeg[b + 1];
    const int half = (se - ss) >> 1;
    int e        = ss + half * wv;
    const int be = wv ? se : (ss + half);

    while (e + 16 <= be) {
        int2 pa[8], pb[8];
        float xa[8], xb[8];
        #pragma unroll
        for (int j = 0; j < 8; ++j) pa[j] = payload[e + j];
        #pragma unroll
        for (int j = 0; j < 8; ++j) pb[j] = payload[e + 8 + j];
        #pragma unroll
        for (int j = 0; j < 8; ++j)
            xa[j] = x[(size_t)(pa[j].x & 0x1FFFF) * 64 + lane];
        #pragma unroll
        for (int j = 0; j < 8; ++j)
            xb[j] = x[(size_t)(pb[j].x & 0x1FFFF) * 64 + lane];
        #pragma unroll
        for (int j = 0; j < 8; ++j)
            ac[(pa[j].x >> 17) * 64 + lane] += __int_as_float(pa[j].y) * xa[j];
        #pragma unroll
        for (int j = 0; j < 8; ++j)
            ac[(pb[j].x >> 17) * 64 + lane] += __int_as_float(pb[j].y) * xb[j];
        e += 16;
    }
    for (; e < be; ++e) {
        const int2 p = payload[e];
        ac[(p.x >> 17) * 64 + lane] +=
            __int_as_float(p.y) * x[(size_t)(p.x & 0x1FFFF) * 64 + lane];
    }
    __syncthreads();

    const int base = b * RPB;
    const int nrow = min(RPB, N - base);
    for (int i = tid; i < nrow * 64; i += 128)
        out[(size_t)base * 64 + i] = acc[0][i] + acc[1][i];
}

// Round-1 fallback (atomic scatter) if ws is too small for binning at all.
static __global__ __launch_bounds__(256) void gtconv_scatter(
    const float* __restrict__ x, const float* __restrict__ h,
    const float* __restrict__ vals, const int* __restrict__ rows,
    const int* __restrict__ cols, float* __restrict__ out, int KE, int E)
{
    const int lane = threadIdx.x & 63;
    int wave = (blockIdx.x * blockDim.x + threadIdx.x) >> 6;
    const int nwaves = (gridDim.x * blockDim.x) >> 6;
    for (int e = wave; e < KE; e += nwaves) {
        float w = h[e / E] * vals[e];
        float xv = x[(size_t)cols[e] * 64 + lane];
        unsafeAtomicAdd(&out[(size_t)rows[e] * 64 + lane], xv * w);
    }
}

extern "C" void kernel_launch(void* const* d_in, const int* in_sizes, int n_in,
                              void* d_out, int out_size, void* d_ws, size_t ws_size,
                              hipStream_t stream) {
    const float* x    = (const float*)d_in[0];
    const float* h    = (const float*)d_in[1];
    const float* vals = (const float*)d_in[2];
    const int*   rows = (const int*)d_in[3];
    const int*   cols = (const int*)d_in[4];
    float* out = (float*)d_out;

    const int K  = in_sizes[1];
    const int KE = in_sizes[2];
    const int E  = KE / K;
    const int F  = 64;
    const int N  = in_sizes[0] / F;
    const int NB      = (N + RPB - 1) / RPB;       // 1563
    const int NSTREAM = NB;                        // 1563 (bucket only)

    const size_t lds_need = (size_t)NSTREAM * 4;   // count/scatter LDS (6.3KB)
    const size_t cnt_off  = 0;
    const size_t cnt_sz   = (size_t)NSTREAM * GWG * 4;
    const size_t ss_off   = cnt_off + cnt_sz;
    const size_t ss_sz    = (size_t)(NSTREAM + 1) * 4;
    const size_t pl_off   = (ss_off + ss_sz + 15) & ~(size_t)15;
    const size_t base_need = pl_off + (size_t)KE * 8;
    const size_t xh_off   = (base_need + 63) & ~(size_t)63;
    const size_t full_need = xh_off + (size_t)N * F * 2;

    if (ws_size < base_need || lds_need > 64 * 1024) {
        hipMemsetAsync(out, 0, (size_t)out_size * sizeof(float), stream);
        gtconv_scatter<<<8192, 256, 0, stream>>>(x, h, vals, rows, cols, out, KE, E);
        return;
    }

    char* ws = (char*)d_ws;
    int*    cnt     = (int*)(ws + cnt_off);
    int*    ssBeg   = (int*)(ws + ss_off);
    int2*   payload = (int2*)(ws + pl_off);
    ushort* xh      = (ushort*)(ws + xh_off);
    const bool use_bf16 = (ws_size >= full_need);

    if (use_bf16) {
        const int n4 = (N * F) / 4;
        convert_kernel<<<(n4 + 255) / 256, 256, 0, stream>>>(x, xh, n4);
    }

    const int chunk = (KE + GWG - 1) / GWG;
    count_kernel<<<GWG, 1024, lds_need, stream>>>(rows, cnt, KE, NSTREAM, chunk);
    scan1_kernel<<<NSTREAM, GWG, 0, stream>>>(cnt, ssBeg);
    scan2_kernel<<<1, 1024, 0, stream>>>(ssBeg, NSTREAM);
    const int total = NSTREAM * GWG;
    scan3_kernel<<<(total + 1023) / 1024, 1024, 0, stream>>>(cnt, ssBeg, total);
    scatter_kernel<<<GWG, 1024, lds_need, stream>>>(rows, cols, vals, h, cnt,
                                                    payload, KE, E, K, NSTREAM, chunk);
    if (use_bf16)
        spmv_bf16_kernel<<<NB, 128, 0, stream>>>(ssBeg, payload, xh, out, N);
    else
        spmv_f32_kernel<<<NB, 128, 0, stream>>>(ssBeg, payload, x, out, N);
}

// Round 14
// 482.823 us; speedup vs baseline: 2.5546x; 1.0541x over previous
//
#include <hip/hip_runtime.h>
#include <hip/hip_bf16.h>

// out = (sum_k h[k] * S_k) @ x  — COO SpMM, bucket-binned, atomic-free accumulate.
//
// Evidence-complete design (r5..r13):
//  * spmv: r11 structure VERBATIM — 2 waves/block, wave wv walks parity
//    stream 2b+wv, SHARED 16KB acc (parity rows disjoint -> race-free),
//    unconditional 16-deep bf16-gather pipeline. 16KB -> 10 blocks/CU cap.
//    (r13's 32KB private copies: occ 17%, 395us. r12's branchy gathers:
//    1134us. r11's: ~60-100us by residual.)
//  * scatter frontier law: streams x WGs/XCD x 64B <= ~1.6MB/XCD when the
//    12.8MB bf16-x copy is L2-resident (r11 3126x16 thrashed: 221MB writes;
//    r12 1563x16 fit: ~55us). Need 3126 parity streams for the spmv ->
//    shrink GWG to 64 (3126 x 8 x 64B = 1.6MB/XCD).
//
// ws: cnt[3126*64] | ssBeg[3127] | pad | payload[KE] int2 | xh[N*64] bf16

#define RPB   64           // rows per bucket
#define SUB   2            // parity classes
#define GWG   64           // count/scatter workgroups (frontier budget!)

static __global__ __launch_bounds__(1024) void count_kernel(
    const int* __restrict__ rows, int* __restrict__ cnt,
    int KE, int NSTREAM, int chunk)
{
    extern __shared__ int hist[];              // NSTREAM ints
    const int g = blockIdx.x;
    for (int j = threadIdx.x; j < NSTREAM; j += blockDim.x) hist[j] = 0;
    __syncthreads();
    const int lo = g * chunk;
    const int hi = min(lo + chunk, KE);
    for (int e = lo + threadIdx.x; e < hi; e += blockDim.x) {
        const int r = rows[e];
        atomicAdd(&hist[((r >> 6) << 1) | (r & 1)], 1);
    }
    __syncthreads();
    for (int j = threadIdx.x; j < NSTREAM; j += blockDim.x)
        cnt[(size_t)j * GWG + g] = hist[j];
}

// B1: per-stream exclusive scan of its GWG counts (in place); total -> ssBeg[s]
static __global__ __launch_bounds__(GWG) void scan1_kernel(
    int* __restrict__ cnt, int* __restrict__ ssBeg)
{
    __shared__ int tmp[GWG];
    const int s = blockIdx.x;
    const int t = threadIdx.x;
    const int v = cnt[(size_t)s * GWG + t];
    tmp[t] = v;
    __syncthreads();
    for (int d = 1; d < GWG; d <<= 1) {
        int u = (t >= d) ? tmp[t - d] : 0;
        __syncthreads();
        tmp[t] += u;
        __syncthreads();
    }
    cnt[(size_t)s * GWG + t] = tmp[t] - v;     // exclusive
    if (t == GWG - 1) ssBeg[s] = tmp[t];       // stream total
}

// B2: exclusive scan of ssBeg[0..n) in place; ssBeg[n] = grand total
static __global__ __launch_bounds__(1024) void scan2_kernel(
    int* __restrict__ a, int n)
{
    __shared__ int sums[1024];
    const int t = threadIdx.x;
    const int chunk = (n + 1023) >> 10;
    const int lo = t * chunk;
    const int hi = min(lo + chunk, n);
    int s = 0;
    for (int i = lo; i < hi; ++i) s += a[i];
    sums[t] = s;
    __syncthreads();
    for (int d = 1; d < 1024; d <<= 1) {
        int v = (t >= d) ? sums[t - d] : 0;
        __syncthreads();
        sums[t] += v;
        __syncthreads();
    }
    int run = (t > 0) ? sums[t - 1] : 0;
    for (int i = lo; i < hi; ++i) {
        const int cv = a[i];
        a[i] = run;
        run += cv;
    }
    if (t == 1023) a[n] = sums[1023];
}

// B3: cnt[s][g] += stream base
static __global__ __launch_bounds__(1024) void scan3_kernel(
    int* __restrict__ cnt, const int* __restrict__ ssBeg, int total)
{
    const int i = blockIdx.x * blockDim.x + threadIdx.x;
    if (i < total) cnt[i] += ssBeg[i >> 6];    // i / GWG (GWG=64)
}

static __global__ __launch_bounds__(1024) void scatter_kernel(
    const int*   __restrict__ rows,
    const int*   __restrict__ cols,
    const float* __restrict__ vals,
    const float* __restrict__ h,
    const int*   __restrict__ cnt,
    int2*        __restrict__ payload,
    int KE, int E, int K, int NSTREAM, int chunk)
{
    extern __shared__ int lcur[];              // NSTREAM cursors
    const int g = blockIdx.x;
    for (int j = threadIdx.x; j < NSTREAM; j += blockDim.x)
        lcur[j] = cnt[(size_t)j * GWG + g];
    __syncthreads();
    const int lo = g * chunk;
    const int hi = min(lo + chunk, KE);
    if (lo >= hi) return;
    const int k0 = lo / E;
    const int k1 = min((hi - 1) / E, K - 1);
    for (int k = k0; k <= k1; ++k) {
        const float hk = h[k];
        const int s0 = max(lo, k * E);
        const int s1 = min(hi, (k + 1) * E);
        for (int e = s0 + threadIdx.x; e < s1; e += blockDim.x) {
            const int r = rows[e];
            const int st = ((r >> 6) << 1) | (r & 1);
            const int pos = atomicAdd(&lcur[st], 1);      // int LDS atomic
            payload[pos] = make_int2(((r & 63) << 17) | cols[e],
                                     __float_as_int(hk * vals[e]));
        }
    }
}

// x (f32) -> xh (bf16), vectorized: float4 in, ushort4 out
static __global__ __launch_bounds__(256) void convert_kernel(
    const float* __restrict__ x, ushort* __restrict__ xh, int n4)
{
    const int i = blockIdx.x * blockDim.x + threadIdx.x;
    if (i >= n4) return;
    const float4 v = ((const float4*)x)[i];
    ushort4 o;
    o.x = __bfloat16_as_ushort(__float2bfloat16(v.x));
    o.y = __bfloat16_as_ushort(__float2bfloat16(v.y));
    o.z = __bfloat16_as_ushort(__float2bfloat16(v.z));
    o.w = __bfloat16_as_ushort(__float2bfloat16(v.w));
    ((ushort4*)xh)[i] = o;
}

// Tier A (r11 verbatim): bf16 gather, wave wv owns parity stream 2b+wv,
// SHARED 16KB acc (parity rows disjoint), unconditional 16-deep pipeline.
static __global__ __launch_bounds__(128) void spmv_bf16_kernel(
    const int*    __restrict__ ssBeg,
    const int2*   __restrict__ payload,
    const ushort* __restrict__ xh,
    float*        __restrict__ out,
    int N)
{
    __shared__ float acc[RPB * 64];            // 16KB
    const int b = blockIdx.x;
    for (int i = threadIdx.x; i < RPB * 64; i += 128) acc[i] = 0.f;
    __syncthreads();

    const int lane = threadIdx.x & 63;
    const int wv   = threadIdx.x >> 6;         // 0..1, owns rows r%2==wv
    const int s    = b * SUB + wv;
    int e        = ssBeg[s];
    const int be = ssBeg[s + 1];

    while (e + 16 <= be) {
        int2 pa[8], pb[8];
        float xa[8], xb[8];
        #pragma unroll
        for (int j = 0; j < 8; ++j) pa[j] = payload[e + j];
        #pragma unroll
        for (int j = 0; j < 8; ++j) pb[j] = payload[e + 8 + j];
        #pragma unroll
        for (int j = 0; j < 8; ++j)
            xa[j] = __bfloat162float(__ushort_as_bfloat16(
                        xh[(size_t)(pa[j].x & 0x1FFFF) * 64 + lane]));
        #pragma unroll
        for (int j = 0; j < 8; ++j)
            xb[j] = __bfloat162float(__ushort_as_bfloat16(
                        xh[(size_t)(pb[j].x & 0x1FFFF) * 64 + lane]));
        #pragma unroll
        for (int j = 0; j < 8; ++j)
            acc[(pa[j].x >> 17) * 64 + lane] += __int_as_float(pa[j].y) * xa[j];
        #pragma unroll
        for (int j = 0; j < 8; ++j)
            acc[(pb[j].x >> 17) * 64 + lane] += __int_as_float(pb[j].y) * xb[j];
        e += 16;
    }
    for (; e < be; ++e) {
        const int2 p = payload[e];
        const float xv = __bfloat162float(__ushort_as_bfloat16(
                             xh[(size_t)(p.x & 0x1FFFF) * 64 + lane]));
        acc[(p.x >> 17) * 64 + lane] += __int_as_float(p.y) * xv;
    }
    __syncthreads();

    const int base = b * RPB;
    const int nrow = min(RPB, N - base);
    for (int i = threadIdx.x; i < nrow * 64; i += 128)
        out[(size_t)base * 64 + i] = acc[i];
}

// Tier B: f32 gather (ws too small for xh), same structure.
static __global__ __launch_bounds__(128) void spmv_f32_kernel(
    const int*  __restrict__ ssBeg,
    const int2* __restrict__ payload,
    const float* __restrict__ x,
    float*       __restrict__ out,
    int N)
{
    __shared__ float acc[RPB * 64];
    const int b = blockIdx.x;
    for (int i = threadIdx.x; i < RPB * 64; i += 128) acc[i] = 0.f;
    __syncthreads();

    const int lane = threadIdx.x & 63;
    const int wv   = threadIdx.x >> 6;
    const int s    = b * SUB + wv;
    int e        = ssBeg[s];
    const int be = ssBeg[s + 1];

    while (e + 16 <= be) {
        int2 pa[8], pb[8];
        float xa[8], xb[8];
        #pragma unroll
        for (int j = 0; j < 8; ++j) pa[j] = payload[e + j];
        #pragma unroll
        for (int j = 0; j < 8; ++j) pb[j] = payload[e + 8 + j];
        #pragma unroll
        for (int j = 0; j < 8; ++j)
            xa[j] = x[(size_t)(pa[j].x & 0x1FFFF) * 64 + lane];
        #pragma unroll
        for (int j = 0; j < 8; ++j)
            xb[j] = x[(size_t)(pb[j].x & 0x1FFFF) * 64 + lane];
        #pragma unroll
        for (int j = 0; j < 8; ++j)
            acc[(pa[j].x >> 17) * 64 + lane] += __int_as_float(pa[j].y) * xa[j];
        #pragma unroll
        for (int j = 0; j < 8; ++j)
            acc[(pb[j].x >> 17) * 64 + lane] += __int_as_float(pb[j].y) * xb[j];
        e += 16;
    }
    for (; e < be; ++e) {
        const int2 p = payload[e];
        acc[(p.x >> 17) * 64 + lane] +=
            __int_as_float(p.y) * x[(size_t)(p.x & 0x1FFFF) * 64 + lane];
    }
    __syncthreads();

    const int base = b * RPB;
    const int nrow = min(RPB, N - base);
    for (int i = threadIdx.x; i < nrow * 64; i += 128)
        out[(size_t)base * 64 + i] = acc[i];
}

// Round-1 fallback (atomic scatter) if ws is too small for binning at all.
static __global__ __launch_bounds__(256) void gtconv_scatter(
    const float* __restrict__ x, const float* __restrict__ h,
    const float* __restrict__ vals, const int* __restrict__ rows,
    const int* __restrict__ cols, float* __restrict__ out, int KE, int E)
{
    const int lane = threadIdx.x & 63;
    int wave = (blockIdx.x * blockDim.x + threadIdx.x) >> 6;
    const int nwaves = (gridDim.x * blockDim.x) >> 6;
    for (int e = wave; e < KE; e += nwaves) {
        float w = h[e / E] * vals[e];
        float xv = x[(size_t)cols[e] * 64 + lane];
        unsafeAtomicAdd(&out[(size_t)rows[e] * 64 + lane], xv * w);
    }
}

extern "C" void kernel_launch(void* const* d_in, const int* in_sizes, int n_in,
                              void* d_out, int out_size, void* d_ws, size_t ws_size,
                              hipStream_t stream) {
    const float* x    = (const float*)d_in[0];
    const float* h    = (const float*)d_in[1];
    const float* vals = (const float*)d_in[2];
    const int*   rows = (const int*)d_in[3];
    const int*   cols = (const int*)d_in[4];
    float* out = (float*)d_out;

    const int K  = in_sizes[1];
    const int KE = in_sizes[2];
    const int E  = KE / K;
    const int F  = 64;
    const int N  = in_sizes[0] / F;
    const int NB      = (N + RPB - 1) / RPB;       // 1563
    const int NSTREAM = NB * SUB;                  // 3126 parity streams

    const size_t lds_need = (size_t)NSTREAM * 4;   // count/scatter LDS (12.5KB)
    const size_t cnt_off  = 0;
    const size_t cnt_sz   = (size_t)NSTREAM * GWG * 4;
    const size_t ss_off   = cnt_off + cnt_sz;
    const size_t ss_sz    = (size_t)(NSTREAM + 1) * 4;
    const size_t pl_off   = (ss_off + ss_sz + 15) & ~(size_t)15;
    const size_t base_need = pl_off + (size_t)KE * 8;
    const size_t xh_off   = (base_need + 63) & ~(size_t)63;
    const size_t full_need = xh_off + (size_t)N * F * 2;

    if (ws_size < base_need || lds_need > 64 * 1024) {
        hipMemsetAsync(out, 0, (size_t)out_size * sizeof(float), stream);
        gtconv_scatter<<<8192, 256, 0, stream>>>(x, h, vals, rows, cols, out, KE, E);
        return;
    }

    char* ws = (char*)d_ws;
    int*    cnt     = (int*)(ws + cnt_off);
    int*    ssBeg   = (int*)(ws + ss_off);
    int2*   payload = (int2*)(ws + pl_off);
    ushort* xh      = (ushort*)(ws + xh_off);
    const bool use_bf16 = (ws_size >= full_need);

    if (use_bf16) {
        const int n4 = (N * F) / 4;
        convert_kernel<<<(n4 + 255) / 256, 256, 0, stream>>>(x, xh, n4);
    }

    const int chunk = (KE + GWG - 1) / GWG;
    count_kernel<<<GWG, 1024, lds_need, stream>>>(rows, cnt, KE, NSTREAM, chunk);
    scan1_kernel<<<NSTREAM, GWG, 0, stream>>>(cnt, ssBeg);
    scan2_kernel<<<1, 1024, 0, stream>>>(ssBeg, NSTREAM);
    const int total = NSTREAM * GWG;
    scan3_kernel<<<(total + 1023) / 1024, 1024, 0, stream>>>(cnt, ssBeg, total);
    scatter_kernel<<<GWG, 1024, lds_need, stream>>>(rows, cols, vals, h, cnt,
                                                    payload, KE, E, K, NSTREAM, chunk);
    if (use_bf16)
        spmv_bf16_kernel<<<NB, 128, 0, stream>>>(ssBeg, payload, xh, out, N);
    else
        spmv_f32_kernel<<<NB, 128, 0, stream>>>(ssBeg, payload, x, out, N);
}